// Round 9
// baseline (112.929 us; speedup 1.0000x reference)
//
#include <hip/hip_runtime.h>
#include <hip/hip_bf16.h>

// ColumnConsistencyLoss: B=16, T=8192, C=128.
// out = mean over columns c with n_c>1 of (q_c - t_c/n_c)/(n_c*C)
//   n_c = # valid rows with seg=c ; q_c = sum z2/z^2 over those rows
//   s[c][j] = sum p_j over those rows ; t_c = sum_j s[c][j]^2
//
// Round-9: round-8 fused structure (softmax -> LDS P in MFMA B-frag order ->
// one-hot mfma_f32_32x32x16_bf16 -> partial slab; HW-verified absmax 0.0)
// with: (1) ntile<->column permutation nt |-> cols {4j+nt} so phase-1 loads
// are float4 (4x fewer VMEM ops) and C-stores are float4-coalesced. Valid
// because t_c = sum_j s^2 is permutation-invariant in j. (2) final_k folded
// into k3 via device atomics + ticket (fused zeroes the scalars first on the
// same stream). ~85 us of dur_us is harness ws-poison/restore at HBM peak
// (round 7/8 rocprof) — not addressable from kernel code.

#define NROWS 131072
#define CC    128
#define NB    256
#define RPB   512   // rows per block

typedef float f32x16 __attribute__((ext_vector_type(16)));
typedef short bf16x8 __attribute__((ext_vector_type(8)));

union U4V { uint4 u; bf16x8 v; };
union H2U { __hip_bfloat162 h; unsigned int u; };

// ---------------- Fused: softmax -> LDS P -> one-hot MFMA -> partial slab ---
// 256 blocks x 1024 thr (16 waves).
// Phase 1 (16 waves): wave w covers ksteps 2w,2w+1; lane = 32q+j5 computes
//   rows rb..rb+7 (half q) x cols 4*j5..4*j5+3 (one float4 per row).
//   P packed so b-frag of (kstep, nt) at lane 32q+j5 = P[k][4*j5+nt].
// Phase 2 (waves 0-3): wave = m-tile, 4 n-tiles, b-frags via ds_read_b128.
__global__ __launch_bounds__(1024) void fused_kernel(
    const float* __restrict__ logits, const int* __restrict__ seg,
    const int* __restrict__ mask, float* __restrict__ slab_s,
    float* __restrict__ slab_n, float* __restrict__ slab_q,
    float* __restrict__ scal, unsigned int* __restrict__ ticket) {
  __shared__ ushort Plds[RPB * CC];        // 128 KiB
  __shared__ int sm[RPB];                  // seg | mask<<16
  __shared__ unsigned int sg4[128];        // packed seg-bytes (255 = invalid)
  __shared__ float n_lds[CC], q_lds[CC];
  const int t = threadIdx.x, b = blockIdx.x;
  if (b == 0 && t == 1023) {               // zero k3's accumulators
    scal[0] = 0.f; scal[1] = 0.f; *ticket = 0u;
  }
  if (t < CC) { n_lds[t] = 0.f; q_lds[t] = 0.f; }
  if (t < RPB) {
    const int r = b * RPB + t;
    sm[t] = seg[r] | (mask[r] << 16);
  }
  __syncthreads();
  if (t < 128) {
    unsigned int w = 0;
#pragma unroll
    for (int k = 0; k < 4; ++k) {
      const int smv = sm[t * 4 + k];
      const unsigned int sv = (smv >> 16) ? (unsigned int)(smv & 0xFFFF) : 255u;
      w |= sv << (8 * k);
    }
    sg4[t] = w;
  }

  const int wave = t >> 6, lane = t & 63;
  const int q = lane >> 5, j5 = lane & 31;
#pragma unroll
  for (int g = 0; g < 2; ++g) {
    const int ts = 2 * wave + g;           // kstep in [0,32)
    const int rb = ts * 16 + q * 8;        // local row base (+i)
    float4 x[8];
#pragma unroll
    for (int i = 0; i < 8; ++i)
      x[i] = ((const float4*)(logits + (size_t)(b * RPB + rb + i) * CC))[j5];
    float inv[8], qr[8];
#pragma unroll
    for (int i = 0; i < 8; ++i) {
      float4 e;
      e.x = __expf(x[i].x); e.y = __expf(x[i].y);
      e.z = __expf(x[i].z); e.w = __expf(x[i].w);
      x[i] = e;
      float z = (e.x + e.y) + (e.z + e.w);
      float z2 = (e.x * e.x + e.y * e.y) + (e.z * e.z + e.w * e.w);
#pragma unroll
      for (int off = 1; off < 32; off <<= 1) {  // 32-lane halves hold rows
        z  += __shfl_xor(z, off, 64);
        z2 += __shfl_xor(z2, off, 64);
      }
      inv[i] = 1.0f / z;
      qr[i] = z2 * inv[i] * inv[i];
    }
#pragma unroll
    for (int nt = 0; nt < 4; ++nt) {
      unsigned int d[4];
#pragma unroll
      for (int k = 0; k < 4; ++k) {
        const float* xa = (const float*)&x[2 * k];
        const float* xb = (const float*)&x[2 * k + 1];
        H2U h;
        h.h = __float22bfloat162_rn(
            make_float2(xa[nt] * inv[2 * k], xb[nt] * inv[2 * k + 1]));
        d[k] = h.u;
      }
      *(uint4*)(Plds + ((size_t)(ts * 4 + nt) * 64 + lane) * 8) =
          make_uint4(d[0], d[1], d[2], d[3]);
    }
    if (j5 == 0) {
#pragma unroll
      for (int i = 0; i < 8; ++i) {
        const int smv = sm[rb + i];
        if (smv >> 16) {
          atomicAdd(&n_lds[smv & 0xFFFF], 1.0f);
          atomicAdd(&q_lds[smv & 0xFFFF], qr[i]);
        }
      }
    }
  }
  __syncthreads();

  // n/q slab writes by otherwise-idle waves 4-7.
  if (t >= 256 && t < 384) slab_n[(t - 256) * NB + b] = n_lds[t - 256];
  else if (t >= 384 && t < 512) slab_q[(t - 384) * NB + b] = q_lds[t - 384];

  if (wave < 4) {
    const int mm = wave * 32 + (lane & 31);
    f32x16 acc0 = {}, acc1 = {}, acc2 = {}, acc3 = {};
    const ushort* pl = Plds + (size_t)lane * 8;
    for (int ks = 0; ks < 32; ++ks) {
      const unsigned int w0 = sg4[ks * 4 + q * 2];
      const unsigned int w1 = sg4[ks * 4 + q * 2 + 1];
      U4V a;
      {
        const unsigned int s0 = w0 & 255u, s1 = (w0 >> 8) & 255u;
        const unsigned int s2 = (w0 >> 16) & 255u, s3 = w0 >> 24;
        const unsigned int s4 = w1 & 255u, s5 = (w1 >> 8) & 255u;
        const unsigned int s6 = (w1 >> 16) & 255u, s7 = w1 >> 24;
        const unsigned int um = (unsigned int)mm;
        a.u = make_uint4(
            (s0 == um ? 0x3F80u : 0u) | (s1 == um ? 0x3F800000u : 0u),
            (s2 == um ? 0x3F80u : 0u) | (s3 == um ? 0x3F800000u : 0u),
            (s4 == um ? 0x3F80u : 0u) | (s5 == um ? 0x3F800000u : 0u),
            (s6 == um ? 0x3F80u : 0u) | (s7 == um ? 0x3F800000u : 0u));
      }
      U4V b0, b1, b2, b3;
      b0.u = *(const uint4*)(pl + (size_t)(ks * 4 + 0) * 512);
      b1.u = *(const uint4*)(pl + (size_t)(ks * 4 + 1) * 512);
      b2.u = *(const uint4*)(pl + (size_t)(ks * 4 + 2) * 512);
      b3.u = *(const uint4*)(pl + (size_t)(ks * 4 + 3) * 512);
      acc0 = __builtin_amdgcn_mfma_f32_32x32x16_bf16(a.v, b0.v, acc0, 0, 0, 0);
      acc1 = __builtin_amdgcn_mfma_f32_32x32x16_bf16(a.v, b1.v, acc1, 0, 0, 0);
      acc2 = __builtin_amdgcn_mfma_f32_32x32x16_bf16(a.v, b2.v, acc2, 0, 0, 0);
      acc3 = __builtin_amdgcn_mfma_f32_32x32x16_bf16(a.v, b3.v, acc3, 0, 0, 0);
    }
    // C/D layout (verified m74/m101 + rounds 7/8 absmax 0.0):
    // n-in-tile = lane&31, row = (reg&3) + 8*(reg>>2) + 4*(lane>>5).
    // ntile nt holds columns 4*j + nt -> accs 0..3 are 4 adjacent columns.
    float* outp = slab_s + (size_t)b * (CC * CC);
    const int jcol = lane & 31;
    const int rbase = (lane >> 5) * 4;
#pragma unroll
    for (int reg = 0; reg < 16; ++reg) {
      const int c = wave * 32 + (reg & 3) + 8 * (reg >> 2) + rbase;
      *(float4*)(outp + c * CC + 4 * jcol) =
          make_float4(acc0[reg], acc1[reg], acc2[reg], acc3[reg]);
    }
  }
}

// ---------------- K3: reduce partials -> colvar -> (atomics) -> out ---------
__global__ __launch_bounds__(1024) void k3_colvar(
    const float* __restrict__ slab_s, const float* __restrict__ slab_n,
    const float* __restrict__ slab_q, float* __restrict__ scal,
    unsigned int* __restrict__ ticket, float* __restrict__ out) {
  const int c = blockIdx.x, t = threadIdx.x;
  const int j = t & 127, g8 = t >> 7;
  const float* base = slab_s + (size_t)g8 * (CC * CC) + (size_t)c * CC + j;
  float acc = 0.f;
#pragma unroll
  for (int i = 0; i < 32; ++i) acc += base[(size_t)(8 * i) * (CC * CC)];
  __shared__ float part[8 * CC];
  part[g8 * CC + j] = acc;
  __syncthreads();
  float tp = 0.f, np = 0.f, qp = 0.f;
  if (t < CC) {
    float s = 0.f;
#pragma unroll
    for (int g = 0; g < 8; ++g) s += part[g * CC + t];
    tp = s * s;
  } else if (t < 2 * CC) {
    const int k = t - CC;
    np = slab_n[c * NB + k] + slab_n[c * NB + k + 128];
  } else if (t < 3 * CC) {
    const int k = t - 2 * CC;
    qp = slab_q[c * NB + k] + slab_q[c * NB + k + 128];
  }
#pragma unroll
  for (int off = 32; off > 0; off >>= 1) {
    tp += __shfl_xor(tp, off, 64);
    np += __shfl_xor(np, off, 64);
    qp += __shfl_xor(qp, off, 64);
  }
  __shared__ float fin[3 * 16];
  if ((t & 63) == 0) {
    const int w = t >> 6;
    fin[w * 3 + 0] = tp; fin[w * 3 + 1] = np; fin[w * 3 + 2] = qp;
  }
  __syncthreads();
  if (t == 0) {
    float tt = 0.f, nn = 0.f, qq = 0.f;
#pragma unroll
    for (int i = 0; i < 16; ++i) {
      tt += fin[i * 3 + 0]; nn += fin[i * 3 + 1]; qq += fin[i * 3 + 2];
    }
    float cv = 0.f, fl = 0.f;
    if (nn > 1.0f) {
      cv = (qq - tt / nn) / (nn * (float)CC);
      fl = 1.f;
    }
    atomicAdd(&scal[0], cv);
    atomicAdd(&scal[1], fl);
    __threadfence();
    const unsigned int old = atomicAdd(ticket, 1u);
    if (old == CC - 1) {                    // last block: all adds visible
      const float total = atomicAdd(&scal[0], 0.f);
      const float count = atomicAdd(&scal[1], 0.f);
      out[0] = (count > 0.f) ? total / fmaxf(count, 1.f) : 0.f;
    }
  }
}

// =================== launch =================================================
extern "C" void kernel_launch(void* const* d_in, const int* in_sizes, int n_in,
                              void* d_out, int out_size, void* d_ws,
                              size_t ws_size, hipStream_t stream) {
  const float* logits = (const float*)d_in[0];
  const int* seg = (const int*)d_in[1];
  const int* mask = (const int*)d_in[2];
  float* out = (float*)d_out;

  // ws layout (~17.1 MB): slab_s f32[256][128][128] | slab_n f32[128][256] |
  // slab_q f32[128][256] | scal[2] | ticket[1]
  float* slab_s = (float*)d_ws;
  float* slab_n = slab_s + (size_t)NB * CC * CC;
  float* slab_q = slab_n + CC * NB;
  float* scal = slab_q + CC * NB;
  unsigned int* ticket = (unsigned int*)(scal + 2);
  fused_kernel<<<NB, 1024, 0, stream>>>(logits, seg, mask, slab_s, slab_n,
                                        slab_q, scal, ticket);
  k3_colvar<<<CC, 1024, 0, stream>>>(slab_s, slab_n, slab_q, scal, ticket,
                                     out);
}